// Round 1
// baseline (5200.817 us; speedup 1.0000x reference)
//
#include <hip/hip_runtime.h>

#define NN 50000
#define DD 512
#define NE 150000

typedef float f32x4 __attribute__((ext_vector_type(4)));
typedef float f32x8 __attribute__((ext_vector_type(8)));
typedef __bf16 bf16x8 __attribute__((ext_vector_type(8)));
typedef unsigned short u16x8 __attribute__((ext_vector_type(8)));

// ---------------- scatter: xin[dst[e]] += h[src[e]] ----------------
// 2 edges per 256-thread block; 128 threads per edge row (float4 each).
__global__ void scatter_k(const float* __restrict__ h, const int* __restrict__ src,
                          const int* __restrict__ dst, float* __restrict__ xin) {
  const int e = blockIdx.x * 2 + (threadIdx.x >> 7);
  const int t = threadIdx.x & 127;
  const int s = src[e];
  const int d = dst[e];
  const float4 v = reinterpret_cast<const float4*>(h + (size_t)s * DD)[t];
  float* xp = xin + (size_t)d * DD + (size_t)t * 4;
  atomicAdd(xp + 0, v.x);
  atomicAdd(xp + 1, v.y);
  atomicAdd(xp + 2, v.z);
  atomicAdd(xp + 3, v.w);
}

// ---------------- GEMM1: Z = bf16( xin @ W1^T ), stats += colsum(z), colsum(z^2)
// A [NN,512] f32 (k-contig), W [512,512] f32 (k-contig). 128x128 tile, BK=64,
// 4 waves (2x2 of 64x64), 16x16x32 bf16 MFMA, padded LDS (LDK=72 -> 144B rows).
__global__ __launch_bounds__(256) void gemm1_k(
    const float* __restrict__ A, const float* __restrict__ W,
    unsigned short* __restrict__ Z, float* __restrict__ stats) {
  constexpr int LDK = 72;
  __shared__ unsigned short lA[128 * LDK];
  __shared__ unsigned short lB[128 * LDK];
  const int tid = threadIdx.x;
  const int brow = blockIdx.y * 128;
  const int bcol = blockIdx.x * 128;
  const int lane = tid & 63;
  const int w = tid >> 6;
  const int wr = (w >> 1) * 64;
  const int wc = (w & 1) * 64;
  const int fr = lane & 15;
  const int fg = lane >> 4;

  f32x4 acc[4][4] = {};

  const int srow = tid >> 3;          // 0..31
  const int scol = (tid & 7) * 8;     // 0..56

  for (int kt = 0; kt < 8; ++kt) {
    const int k0 = kt * 64 + scol;
    __syncthreads();
#pragma unroll
    for (int p = 0; p < 4; ++p) {
      const int r = srow + 32 * p;
      {  // A tile (guarded M-tail)
        const int gr = brow + r;
        f32x8 vf = {};
        if (gr < NN) {
          const f32x4* g = reinterpret_cast<const f32x4*>(A + (size_t)gr * DD + k0);
          f32x4 v0 = g[0], v1 = g[1];
          vf[0] = v0[0]; vf[1] = v0[1]; vf[2] = v0[2]; vf[3] = v0[3];
          vf[4] = v1[0]; vf[5] = v1[1]; vf[6] = v1[2]; vf[7] = v1[3];
        }
        *reinterpret_cast<bf16x8*>(&lA[r * LDK + scol]) = __builtin_convertvector(vf, bf16x8);
      }
      {  // B tile (always full: N=512)
        const f32x4* g = reinterpret_cast<const f32x4*>(W + (size_t)(bcol + r) * DD + k0);
        f32x4 v0 = g[0], v1 = g[1];
        f32x8 vf;
        vf[0] = v0[0]; vf[1] = v0[1]; vf[2] = v0[2]; vf[3] = v0[3];
        vf[4] = v1[0]; vf[5] = v1[1]; vf[6] = v1[2]; vf[7] = v1[3];
        *reinterpret_cast<bf16x8*>(&lB[r * LDK + scol]) = __builtin_convertvector(vf, bf16x8);
      }
    }
    __syncthreads();
#pragma unroll
    for (int kk = 0; kk < 2; ++kk) {
      bf16x8 av[4], bv[4];
#pragma unroll
      for (int i = 0; i < 4; ++i)
        av[i] = *reinterpret_cast<const bf16x8*>(&lA[(wr + i * 16 + fr) * LDK + kk * 32 + fg * 8]);
#pragma unroll
      for (int j = 0; j < 4; ++j)
        bv[j] = *reinterpret_cast<const bf16x8*>(&lB[(wc + j * 16 + fr) * LDK + kk * 32 + fg * 8]);
#pragma unroll
      for (int i = 0; i < 4; ++i)
#pragma unroll
        for (int j = 0; j < 4; ++j)
          acc[i][j] = __builtin_amdgcn_mfma_f32_16x16x32_bf16(av[i], bv[j], acc[i][j], 0, 0, 0);
    }
  }

  // epilogue: write z (bf16) + per-column sum/sumsq atomics
#pragma unroll
  for (int j = 0; j < 4; ++j) {
    const int col = bcol + wc + j * 16 + fr;
    float s1 = 0.f, s2 = 0.f;
#pragma unroll
    for (int i = 0; i < 4; ++i) {
      const int rb = brow + wr + i * 16 + fg * 4;
#pragma unroll
      for (int r = 0; r < 4; ++r) {
        const float v = acc[i][j][r];
        s1 += v;
        s2 += v * v;   // pad rows have acc==0 -> contribute nothing
        if (rb + r < NN) {
          __bf16 b = (__bf16)v;
          Z[(size_t)(rb + r) * DD + col] = __builtin_bit_cast(unsigned short, b);
        }
      }
    }
    s1 += __shfl_down(s1, 32);
    s2 += __shfl_down(s2, 32);
    s1 += __shfl_down(s1, 16);
    s2 += __shfl_down(s2, 16);
    if (lane < 16) {
      atomicAdd(&stats[col], s1);
      atomicAdd(&stats[DD + col], s2);
    }
  }
}

// ---------------- BN finalize: scale = gamma*rsqrt(var+eps), shift = beta - mu*scale
__global__ void bnfin_k(const float* __restrict__ stats, const float* __restrict__ gamma,
                        const float* __restrict__ beta, float* __restrict__ scsh) {
  const int n = threadIdx.x;
  const float inv = 1.0f / (float)NN;
  const float mu = stats[n] * inv;
  const float var = stats[DD + n] * inv - mu * mu;
  const float sc = rsqrtf(var + 1e-5f) * gamma[n];
  scsh[n] = sc;
  scsh[DD + n] = beta[n] - mu * sc;
}

// ---------------- GEMM2: H = relu(z*scale+shift) @ W2^T + b2, fused colsum
__global__ __launch_bounds__(256) void gemm2_k(
    const unsigned short* __restrict__ Zin, const float* __restrict__ W,
    const float* __restrict__ scsh, const float* __restrict__ b2,
    float* __restrict__ H, float* __restrict__ colsum,
    const int write_h, const int do_colsum) {
  constexpr int LDK = 72;
  __shared__ unsigned short lA[128 * LDK];
  __shared__ unsigned short lB[128 * LDK];
  const int tid = threadIdx.x;
  const int brow = blockIdx.y * 128;
  const int bcol = blockIdx.x * 128;
  const int lane = tid & 63;
  const int w = tid >> 6;
  const int wr = (w >> 1) * 64;
  const int wc = (w & 1) * 64;
  const int fr = lane & 15;
  const int fg = lane >> 4;

  f32x4 acc[4][4] = {};

  const int srow = tid >> 3;
  const int scol = (tid & 7) * 8;

  for (int kt = 0; kt < 8; ++kt) {
    const int k0 = kt * 64 + scol;
    __syncthreads();
#pragma unroll
    for (int p = 0; p < 4; ++p) {
      const int r = srow + 32 * p;
      {  // A tile: bf16 z -> BN affine -> relu -> bf16 (pad rows forced to 0)
        const int gr = brow + r;
        f32x8 vf = {};
        if (gr < NN) {
          u16x8 zv = *reinterpret_cast<const u16x8*>(Zin + (size_t)gr * DD + k0);
          f32x8 zf = __builtin_convertvector(__builtin_bit_cast(bf16x8, zv), f32x8);
          const f32x4* scp = reinterpret_cast<const f32x4*>(scsh + k0);
          const f32x4* shp = reinterpret_cast<const f32x4*>(scsh + DD + k0);
          f32x4 sc0 = scp[0], sc1 = scp[1], sh0 = shp[0], sh1 = shp[1];
#pragma unroll
          for (int q = 0; q < 4; ++q) {
            vf[q]     = fmaxf(zf[q]     * sc0[q] + sh0[q], 0.f);
            vf[q + 4] = fmaxf(zf[q + 4] * sc1[q] + sh1[q], 0.f);
          }
        }
        *reinterpret_cast<bf16x8*>(&lA[r * LDK + scol]) = __builtin_convertvector(vf, bf16x8);
      }
      {  // B tile
        const f32x4* g = reinterpret_cast<const f32x4*>(W + (size_t)(bcol + r) * DD + k0);
        f32x4 v0 = g[0], v1 = g[1];
        f32x8 vf;
        vf[0] = v0[0]; vf[1] = v0[1]; vf[2] = v0[2]; vf[3] = v0[3];
        vf[4] = v1[0]; vf[5] = v1[1]; vf[6] = v1[2]; vf[7] = v1[3];
        *reinterpret_cast<bf16x8*>(&lB[r * LDK + scol]) = __builtin_convertvector(vf, bf16x8);
      }
    }
    __syncthreads();
#pragma unroll
    for (int kk = 0; kk < 2; ++kk) {
      bf16x8 av[4], bv[4];
#pragma unroll
      for (int i = 0; i < 4; ++i)
        av[i] = *reinterpret_cast<const bf16x8*>(&lA[(wr + i * 16 + fr) * LDK + kk * 32 + fg * 8]);
#pragma unroll
      for (int j = 0; j < 4; ++j)
        bv[j] = *reinterpret_cast<const bf16x8*>(&lB[(wc + j * 16 + fr) * LDK + kk * 32 + fg * 8]);
#pragma unroll
      for (int i = 0; i < 4; ++i)
#pragma unroll
        for (int j = 0; j < 4; ++j)
          acc[i][j] = __builtin_amdgcn_mfma_f32_16x16x32_bf16(av[i], bv[j], acc[i][j], 0, 0, 0);
    }
  }

#pragma unroll
  for (int j = 0; j < 4; ++j) {
    const int col = bcol + wc + j * 16 + fr;
    const float bb = b2[col];
    float s1 = 0.f;
#pragma unroll
    for (int i = 0; i < 4; ++i) {
      const int rb = brow + wr + i * 16 + fg * 4;
#pragma unroll
      for (int r = 0; r < 4; ++r) {
        const float v = acc[i][j][r];
        s1 += v;  // pad rows: acc==0
        if (write_h && (rb + r < NN)) H[(size_t)(rb + r) * DD + col] = v + bb;
      }
    }
    if (do_colsum) {
      s1 += __shfl_down(s1, 32);
      s1 += __shfl_down(s1, 16);
      if (lane < 16) atomicAdd(&colsum[col], s1);
    }
  }
}

// ---------------- final outputs: mean over nodes (+ b2, which was excluded from colsum)
__global__ void out_k(const float* __restrict__ colsum, const float* __restrict__ b2_all,
                      float* __restrict__ out) {
  const int n = threadIdx.x;
  const float inv = 1.0f / (float)NN;
  out[n]      = colsum[DD + n] * inv + b2_all[3 * DD + n];  // outs[-1] = layer idx 3
  out[DD + n] = colsum[n] * inv      + b2_all[2 * DD + n];  // outs[-2] = layer idx 2
}

extern "C" void kernel_launch(void* const* d_in, const int* in_sizes, int n_in,
                              void* d_out, int out_size, void* d_ws, size_t ws_size,
                              hipStream_t stream) {
  const float* x     = (const float*)d_in[0];
  const float* W1    = (const float*)d_in[1];
  // d_in[2] = b1: cancels exactly in training-mode BatchNorm -> unused
  const float* gamma = (const float*)d_in[3];
  const float* beta  = (const float*)d_in[4];
  const float* W2    = (const float*)d_in[5];
  const float* b2    = (const float*)d_in[6];
  const int*   src   = (const int*)d_in[7];
  const int*   dst   = (const int*)d_in[8];
  float* out = (float*)d_out;

  char* ws = (char*)d_ws;
  float*          xin    = (float*)(ws);                     // 102,400,000 B
  float*          h      = (float*)(ws + 102400000);         // 102,400,000 B
  unsigned short* z      = (unsigned short*)(ws + 204800000);// 51,200,000 B
  float*          stats  = (float*)(ws + 256000000);         // 4 KB (sum, sumsq)
  float*          colsum = (float*)(ws + 256004096);         // 4 KB (2 slots)
  float*          scsh   = (float*)(ws + 256008192);         // 4 KB (scale, shift)

  const size_t hbytes = (size_t)NN * DD * sizeof(float);
  hipMemsetAsync(colsum, 0, 2 * DD * sizeof(float), stream);

  dim3 gg(DD / 128, (NN + 127) / 128);  // (4, 391)
  const float* hcur = x;
  for (int l = 0; l < 4; ++l) {
    hipMemcpyAsync(xin, hcur, hbytes, hipMemcpyDeviceToDevice, stream);
    scatter_k<<<NE / 2, 256, 0, stream>>>(hcur, src, dst, xin);
    hipMemsetAsync(stats, 0, 2 * DD * sizeof(float), stream);
    gemm1_k<<<gg, 256, 0, stream>>>(xin, W1 + (size_t)l * DD * DD, z, stats);
    bnfin_k<<<1, DD, 0, stream>>>(stats, gamma + l * DD, beta + l * DD, scsh);
    const int slot = (l == 2) ? 0 : ((l == 3) ? 1 : -1);
    gemm2_k<<<gg, 256, 0, stream>>>(z, W2 + (size_t)l * DD * DD, scsh, b2 + l * DD,
                                    h, colsum + (slot == 1 ? DD : 0),
                                    (l < 3) ? 1 : 0, (slot >= 0) ? 1 : 0);
    hcur = h;
  }
  out_k<<<1, DD, 0, stream>>>(colsum, b2, out);
}

// Round 2
// 1105.308 us; speedup vs baseline: 4.7053x; 4.7053x over previous
//
#include <hip/hip_runtime.h>

#define NN 50000
#define DD 512
#define NE 150000

typedef float f32x4 __attribute__((ext_vector_type(4)));
typedef float f32x8 __attribute__((ext_vector_type(8)));
typedef __bf16 bf16x8 __attribute__((ext_vector_type(8)));
typedef unsigned short u16x8 __attribute__((ext_vector_type(8)));

// ============ CSR build ============
__global__ void count_k(const int* __restrict__ dst, int* __restrict__ cnt) {
  const int e = blockIdx.x * 256 + threadIdx.x;
  if (e < NE) atomicAdd(&cnt[dst[e]], 1);
}

// single-block exclusive scan of cnt[0..NN) -> rowptr[0..NN], cursor copy
__global__ __launch_bounds__(1024) void scan_k(const int* __restrict__ cnt,
                                               int* __restrict__ rowptr,
                                               int* __restrict__ cursor) {
  __shared__ int wsum[16];
  __shared__ int base_s;
  if (threadIdx.x == 0) base_s = 0;
  __syncthreads();
  const int lane = threadIdx.x & 63;
  const int wid = threadIdx.x >> 6;
  for (int c0 = 0; c0 < NN; c0 += 1024) {
    const int i = c0 + threadIdx.x;
    const int v = (i < NN) ? cnt[i] : 0;
    int incl = v;
#pragma unroll
    for (int d = 1; d < 64; d <<= 1) {
      int t = __shfl_up(incl, d);
      if (lane >= d) incl += t;
    }
    if (lane == 63) wsum[wid] = incl;
    __syncthreads();
    if (wid == 0 && lane < 16) {
      int wv = wsum[lane];
#pragma unroll
      for (int d = 1; d < 16; d <<= 1) {
        int t = __shfl_up(wv, d);
        if (lane >= d) wv += t;
      }
      wsum[lane] = wv;  // inclusive wave-sum scan
    }
    __syncthreads();
    const int waveoff = wid ? wsum[wid - 1] : 0;
    const int excl = base_s + waveoff + incl - v;
    if (i < NN) {
      rowptr[i] = excl;
      cursor[i] = excl;
    }
    __syncthreads();
    if (threadIdx.x == 0) base_s += wsum[15];
    __syncthreads();
  }
  if (threadIdx.x == 0) rowptr[NN] = base_s;
}

__global__ void fill_k(const int* __restrict__ src, const int* __restrict__ dst,
                       int* __restrict__ cursor, int* __restrict__ csrc) {
  const int e = blockIdx.x * 256 + threadIdx.x;
  if (e < NE) {
    const int pos = atomicAdd(&cursor[dst[e]], 1);
    csrc[pos] = src[e];
  }
}

// ============ aggregation: xin[v] = bf16( h[v] + sum_{u->v} h[u] ) ============
// one wave per node; lane covers 8 features.
__global__ __launch_bounds__(256) void agg_f32_k(const float* __restrict__ h,
                                                 const int* __restrict__ rowptr,
                                                 const int* __restrict__ csrc,
                                                 unsigned short* __restrict__ xout) {
  const int node = blockIdx.x * 4 + (threadIdx.x >> 6);
  const int lane = threadIdx.x & 63;
  const f32x4* row = reinterpret_cast<const f32x4*>(h + (size_t)node * DD + lane * 8);
  f32x4 a0 = row[0], a1 = row[1];
  const int p1 = rowptr[node + 1];
  for (int p = rowptr[node]; p < p1; ++p) {
    const int s = csrc[p];
    const f32x4* rs = reinterpret_cast<const f32x4*>(h + (size_t)s * DD + lane * 8);
    a0 += rs[0];
    a1 += rs[1];
  }
  f32x8 vf;
  vf[0] = a0[0]; vf[1] = a0[1]; vf[2] = a0[2]; vf[3] = a0[3];
  vf[4] = a1[0]; vf[5] = a1[1]; vf[6] = a1[2]; vf[7] = a1[3];
  *reinterpret_cast<bf16x8*>(xout + (size_t)node * DD + lane * 8) =
      __builtin_convertvector(vf, bf16x8);
}

__global__ __launch_bounds__(256) void agg_bf16_k(const unsigned short* __restrict__ h,
                                                  const int* __restrict__ rowptr,
                                                  const int* __restrict__ csrc,
                                                  unsigned short* __restrict__ xout) {
  const int node = blockIdx.x * 4 + (threadIdx.x >> 6);
  const int lane = threadIdx.x & 63;
  u16x8 sv = *reinterpret_cast<const u16x8*>(h + (size_t)node * DD + lane * 8);
  f32x8 acc = __builtin_convertvector(__builtin_bit_cast(bf16x8, sv), f32x8);
  const int p1 = rowptr[node + 1];
  for (int p = rowptr[node]; p < p1; ++p) {
    const int s = csrc[p];
    u16x8 rv = *reinterpret_cast<const u16x8*>(h + (size_t)s * DD + lane * 8);
    acc += __builtin_convertvector(__builtin_bit_cast(bf16x8, rv), f32x8);
  }
  *reinterpret_cast<bf16x8*>(xout + (size_t)node * DD + lane * 8) =
      __builtin_convertvector(acc, bf16x8);
}

// ============ GEMM1: Z = bf16( xin @ W1^T ), stats += colsum(z), colsum(z^2) ============
__global__ __launch_bounds__(256) void gemm1_k(
    const unsigned short* __restrict__ A, const float* __restrict__ W,
    unsigned short* __restrict__ Z, float* __restrict__ stats) {
  constexpr int LDK = 72;
  __shared__ unsigned short lA[128 * LDK];
  __shared__ unsigned short lB[128 * LDK];
  const int tid = threadIdx.x;
  const int brow = blockIdx.y * 128;
  const int bcol = blockIdx.x * 128;
  const int lane = tid & 63;
  const int w = tid >> 6;
  const int wr = (w >> 1) * 64;
  const int wc = (w & 1) * 64;
  const int fr = lane & 15;
  const int fg = lane >> 4;

  f32x4 acc[4][4] = {};

  const int srow = tid >> 3;
  const int scol = (tid & 7) * 8;

  for (int kt = 0; kt < 8; ++kt) {
    const int k0 = kt * 64 + scol;
    __syncthreads();
#pragma unroll
    for (int p = 0; p < 4; ++p) {
      const int r = srow + 32 * p;
      {  // A tile: already bf16, straight copy (guarded M-tail, pad=0)
        const int gr = brow + r;
        u16x8 zv = {};
        if (gr < NN) zv = *reinterpret_cast<const u16x8*>(A + (size_t)gr * DD + k0);
        *reinterpret_cast<u16x8*>(&lA[r * LDK + scol]) = zv;
      }
      {  // B tile: fp32 W -> bf16
        const f32x4* g = reinterpret_cast<const f32x4*>(W + (size_t)(bcol + r) * DD + k0);
        f32x4 v0 = g[0], v1 = g[1];
        f32x8 vf;
        vf[0] = v0[0]; vf[1] = v0[1]; vf[2] = v0[2]; vf[3] = v0[3];
        vf[4] = v1[0]; vf[5] = v1[1]; vf[6] = v1[2]; vf[7] = v1[3];
        *reinterpret_cast<bf16x8*>(&lB[r * LDK + scol]) = __builtin_convertvector(vf, bf16x8);
      }
    }
    __syncthreads();
#pragma unroll
    for (int kk = 0; kk < 2; ++kk) {
      bf16x8 av[4], bv[4];
#pragma unroll
      for (int i = 0; i < 4; ++i)
        av[i] = *reinterpret_cast<const bf16x8*>(&lA[(wr + i * 16 + fr) * LDK + kk * 32 + fg * 8]);
#pragma unroll
      for (int j = 0; j < 4; ++j)
        bv[j] = *reinterpret_cast<const bf16x8*>(&lB[(wc + j * 16 + fr) * LDK + kk * 32 + fg * 8]);
#pragma unroll
      for (int i = 0; i < 4; ++i)
#pragma unroll
        for (int j = 0; j < 4; ++j)
          acc[i][j] = __builtin_amdgcn_mfma_f32_16x16x32_bf16(av[i], bv[j], acc[i][j], 0, 0, 0);
    }
  }

#pragma unroll
  for (int j = 0; j < 4; ++j) {
    const int col = bcol + wc + j * 16 + fr;
    float s1 = 0.f, s2 = 0.f;
#pragma unroll
    for (int i = 0; i < 4; ++i) {
      const int rb = brow + wr + i * 16 + fg * 4;
#pragma unroll
      for (int r = 0; r < 4; ++r) {
        const float v = acc[i][j][r];
        s1 += v;
        s2 += v * v;  // pad rows have acc==0 -> contribute nothing
        if (rb + r < NN) {
          __bf16 b = (__bf16)v;
          Z[(size_t)(rb + r) * DD + col] = __builtin_bit_cast(unsigned short, b);
        }
      }
    }
    s1 += __shfl_down(s1, 32);
    s2 += __shfl_down(s2, 32);
    s1 += __shfl_down(s1, 16);
    s2 += __shfl_down(s2, 16);
    if (lane < 16) {
      atomicAdd(&stats[col], s1);
      atomicAdd(&stats[DD + col], s2);
    }
  }
}

// ============ BN finalize ============
__global__ void bnfin_k(const float* __restrict__ stats, const float* __restrict__ gamma,
                        const float* __restrict__ beta, float* __restrict__ scsh) {
  const int n = threadIdx.x;
  const float inv = 1.0f / (float)NN;
  const float mu = stats[n] * inv;
  const float var = stats[DD + n] * inv - mu * mu;
  const float sc = rsqrtf(var + 1e-5f) * gamma[n];
  scsh[n] = sc;
  scsh[DD + n] = beta[n] - mu * sc;
}

// ============ GEMM2: H = bf16(relu(z*scale+shift) @ W2^T + b2), fused colsum ============
__global__ __launch_bounds__(256) void gemm2_k(
    const unsigned short* __restrict__ Zin, const float* __restrict__ W,
    const float* __restrict__ scsh, const float* __restrict__ b2,
    unsigned short* __restrict__ H, float* __restrict__ colsum,
    const int write_h, const int do_colsum) {
  constexpr int LDK = 72;
  __shared__ unsigned short lA[128 * LDK];
  __shared__ unsigned short lB[128 * LDK];
  const int tid = threadIdx.x;
  const int brow = blockIdx.y * 128;
  const int bcol = blockIdx.x * 128;
  const int lane = tid & 63;
  const int w = tid >> 6;
  const int wr = (w >> 1) * 64;
  const int wc = (w & 1) * 64;
  const int fr = lane & 15;
  const int fg = lane >> 4;

  f32x4 acc[4][4] = {};

  const int srow = tid >> 3;
  const int scol = (tid & 7) * 8;

  for (int kt = 0; kt < 8; ++kt) {
    const int k0 = kt * 64 + scol;
    __syncthreads();
#pragma unroll
    for (int p = 0; p < 4; ++p) {
      const int r = srow + 32 * p;
      {  // A tile: bf16 z -> BN affine -> relu -> bf16 (pad rows forced to 0)
        const int gr = brow + r;
        f32x8 vf = {};
        if (gr < NN) {
          u16x8 zv = *reinterpret_cast<const u16x8*>(Zin + (size_t)gr * DD + k0);
          f32x8 zf = __builtin_convertvector(__builtin_bit_cast(bf16x8, zv), f32x8);
          const f32x4* scp = reinterpret_cast<const f32x4*>(scsh + k0);
          const f32x4* shp = reinterpret_cast<const f32x4*>(scsh + DD + k0);
          f32x4 sc0 = scp[0], sc1 = scp[1], sh0 = shp[0], sh1 = shp[1];
#pragma unroll
          for (int q = 0; q < 4; ++q) {
            vf[q]     = fmaxf(zf[q]     * sc0[q] + sh0[q], 0.f);
            vf[q + 4] = fmaxf(zf[q + 4] * sc1[q] + sh1[q], 0.f);
          }
        }
        *reinterpret_cast<bf16x8*>(&lA[r * LDK + scol]) = __builtin_convertvector(vf, bf16x8);
      }
      {  // B tile
        const f32x4* g = reinterpret_cast<const f32x4*>(W + (size_t)(bcol + r) * DD + k0);
        f32x4 v0 = g[0], v1 = g[1];
        f32x8 vf;
        vf[0] = v0[0]; vf[1] = v0[1]; vf[2] = v0[2]; vf[3] = v0[3];
        vf[4] = v1[0]; vf[5] = v1[1]; vf[6] = v1[2]; vf[7] = v1[3];
        *reinterpret_cast<bf16x8*>(&lB[r * LDK + scol]) = __builtin_convertvector(vf, bf16x8);
      }
    }
    __syncthreads();
#pragma unroll
    for (int kk = 0; kk < 2; ++kk) {
      bf16x8 av[4], bv[4];
#pragma unroll
      for (int i = 0; i < 4; ++i)
        av[i] = *reinterpret_cast<const bf16x8*>(&lA[(wr + i * 16 + fr) * LDK + kk * 32 + fg * 8]);
#pragma unroll
      for (int j = 0; j < 4; ++j)
        bv[j] = *reinterpret_cast<const bf16x8*>(&lB[(wc + j * 16 + fr) * LDK + kk * 32 + fg * 8]);
#pragma unroll
      for (int i = 0; i < 4; ++i)
#pragma unroll
        for (int j = 0; j < 4; ++j)
          acc[i][j] = __builtin_amdgcn_mfma_f32_16x16x32_bf16(av[i], bv[j], acc[i][j], 0, 0, 0);
    }
  }

#pragma unroll
  for (int j = 0; j < 4; ++j) {
    const int col = bcol + wc + j * 16 + fr;
    const float bb = b2[col];
    float s1 = 0.f;
#pragma unroll
    for (int i = 0; i < 4; ++i) {
      const int rb = brow + wr + i * 16 + fg * 4;
#pragma unroll
      for (int r = 0; r < 4; ++r) {
        const float v = acc[i][j][r];
        s1 += v;  // pad rows: acc==0
        if (write_h && (rb + r < NN)) {
          __bf16 b = (__bf16)(v + bb);
          H[(size_t)(rb + r) * DD + col] = __builtin_bit_cast(unsigned short, b);
        }
      }
    }
    if (do_colsum) {
      s1 += __shfl_down(s1, 32);
      s1 += __shfl_down(s1, 16);
      if (lane < 16) atomicAdd(&colsum[col], s1);
    }
  }
}

// ============ final outputs ============
__global__ void out_k(const float* __restrict__ colsum, const float* __restrict__ b2_all,
                      float* __restrict__ out) {
  const int n = threadIdx.x;
  const float inv = 1.0f / (float)NN;
  out[n]      = colsum[DD + n] * inv + b2_all[3 * DD + n];  // outs[-1] = layer 3
  out[DD + n] = colsum[n] * inv      + b2_all[2 * DD + n];  // outs[-2] = layer 2
}

extern "C" void kernel_launch(void* const* d_in, const int* in_sizes, int n_in,
                              void* d_out, int out_size, void* d_ws, size_t ws_size,
                              hipStream_t stream) {
  const float* x     = (const float*)d_in[0];
  const float* W1    = (const float*)d_in[1];
  // d_in[2] = b1: cancels exactly in training-mode BatchNorm -> unused
  const float* gamma = (const float*)d_in[3];
  const float* beta  = (const float*)d_in[4];
  const float* W2    = (const float*)d_in[5];
  const float* b2    = (const float*)d_in[6];
  const int*   src   = (const int*)d_in[7];
  const int*   dst   = (const int*)d_in[8];
  float* out = (float*)d_out;

  char* ws = (char*)d_ws;
  unsigned short* xin    = (unsigned short*)(ws);               // 51,200,000 B
  unsigned short* z      = (unsigned short*)(ws + 51200000);    // 51,200,000 B
  unsigned short* h      = (unsigned short*)(ws + 102400000);   // 51,200,000 B
  int*            rowptr = (int*)(ws + 153600000);              // (NN+1)*4
  int*            cursor = (int*)(ws + 153900000);              // NN*4
  int*            csrc   = (int*)(ws + 154200000);              // NE*4
  float*          stats  = (float*)(ws + 155000000);            // 2*DD f32
  float*          colsum = (float*)(ws + 155004096);            // 2*DD f32
  float*          scsh   = (float*)(ws + 155008192);            // 2*DD f32

  // ---- CSR build (once per call, reused by all 4 layers) ----
  hipMemsetAsync(cursor, 0, NN * sizeof(int), stream);
  count_k<<<(NE + 255) / 256, 256, 0, stream>>>(dst, cursor);
  scan_k<<<1, 1024, 0, stream>>>(cursor, rowptr, cursor);
  fill_k<<<(NE + 255) / 256, 256, 0, stream>>>(src, dst, cursor, csrc);

  hipMemsetAsync(colsum, 0, 2 * DD * sizeof(float), stream);

  dim3 gg(DD / 128, (NN + 127) / 128);  // (4, 391)
  for (int l = 0; l < 4; ++l) {
    if (l == 0)
      agg_f32_k<<<NN / 4, 256, 0, stream>>>(x, rowptr, csrc, xin);
    else
      agg_bf16_k<<<NN / 4, 256, 0, stream>>>(h, rowptr, csrc, xin);
    hipMemsetAsync(stats, 0, 2 * DD * sizeof(float), stream);
    gemm1_k<<<gg, 256, 0, stream>>>(xin, W1 + (size_t)l * DD * DD, z, stats);
    bnfin_k<<<1, DD, 0, stream>>>(stats, gamma + l * DD, beta + l * DD, scsh);
    const int slot = (l == 2) ? 0 : ((l == 3) ? 1 : -1);
    gemm2_k<<<gg, 256, 0, stream>>>(z, W2 + (size_t)l * DD * DD, scsh, b2 + l * DD,
                                    h, colsum + (slot == 1 ? DD : 0),
                                    (l < 3) ? 1 : 0, (slot >= 0) ? 1 : 0);
  }
  out_k<<<1, DD, 0, stream>>>(colsum, b2, out);
}

// Round 3
// 888.672 us; speedup vs baseline: 5.8523x; 1.2438x over previous
//
#include <hip/hip_runtime.h>

#define NN 50000
#define MPAD 50176  // 392 * 128
#define DD 512
#define NE 150000

typedef float f32x4 __attribute__((ext_vector_type(4)));
typedef float f32x8 __attribute__((ext_vector_type(8)));
typedef __bf16 bf16x8 __attribute__((ext_vector_type(8)));
typedef unsigned short u16x8 __attribute__((ext_vector_type(8)));

__device__ __forceinline__ void gload16(const void* g, void* l) {
  __builtin_amdgcn_global_load_lds((const __attribute__((address_space(1))) void*)g,
                                   (__attribute__((address_space(3))) void*)l, 16, 0, 0);
}

// ============ weight convert: f32 -> bf16, all 4 layers of W1 and W2 ============
__global__ void wconv_k(const float* __restrict__ W1, const float* __restrict__ W2,
                        unsigned short* __restrict__ o1, unsigned short* __restrict__ o2) {
  const size_t i = ((size_t)blockIdx.x * 256 + threadIdx.x) * 8;
  {
    const f32x4* g = reinterpret_cast<const f32x4*>(W1 + i);
    f32x4 a = g[0], b = g[1];
    f32x8 v;
    v[0]=a[0]; v[1]=a[1]; v[2]=a[2]; v[3]=a[3]; v[4]=b[0]; v[5]=b[1]; v[6]=b[2]; v[7]=b[3];
    *reinterpret_cast<bf16x8*>(o1 + i) = __builtin_convertvector(v, bf16x8);
  }
  {
    const f32x4* g = reinterpret_cast<const f32x4*>(W2 + i);
    f32x4 a = g[0], b = g[1];
    f32x8 v;
    v[0]=a[0]; v[1]=a[1]; v[2]=a[2]; v[3]=a[3]; v[4]=b[0]; v[5]=b[1]; v[6]=b[2]; v[7]=b[3];
    *reinterpret_cast<bf16x8*>(o2 + i) = __builtin_convertvector(v, bf16x8);
  }
}

// ============ CSR build ============
__global__ void count_k(const int* __restrict__ dst, int* __restrict__ cnt) {
  const int e = blockIdx.x * 256 + threadIdx.x;
  if (e < NE) atomicAdd(&cnt[dst[e]], 1);
}

__global__ __launch_bounds__(1024) void scan_k(const int* __restrict__ cnt,
                                               int* __restrict__ rowptr,
                                               int* __restrict__ cursor) {
  __shared__ int wsum[16];
  __shared__ int base_s;
  if (threadIdx.x == 0) base_s = 0;
  __syncthreads();
  const int lane = threadIdx.x & 63;
  const int wid = threadIdx.x >> 6;
  for (int c0 = 0; c0 < NN; c0 += 1024) {
    const int i = c0 + threadIdx.x;
    const int v = (i < NN) ? cnt[i] : 0;
    int incl = v;
#pragma unroll
    for (int d = 1; d < 64; d <<= 1) {
      int t = __shfl_up(incl, d);
      if (lane >= d) incl += t;
    }
    if (lane == 63) wsum[wid] = incl;
    __syncthreads();
    if (wid == 0 && lane < 16) {
      int wv = wsum[lane];
#pragma unroll
      for (int d = 1; d < 16; d <<= 1) {
        int t = __shfl_up(wv, d);
        if (lane >= d) wv += t;
      }
      wsum[lane] = wv;
    }
    __syncthreads();
    const int waveoff = wid ? wsum[wid - 1] : 0;
    const int excl = base_s + waveoff + incl - v;
    if (i < NN) {
      rowptr[i] = excl;
      cursor[i] = excl;
    }
    __syncthreads();
    if (threadIdx.x == 0) base_s += wsum[15];
    __syncthreads();
  }
  if (threadIdx.x == 0) rowptr[NN] = base_s;
}

__global__ void fill_k(const int* __restrict__ src, const int* __restrict__ dst,
                       int* __restrict__ cursor, int* __restrict__ csrc) {
  const int e = blockIdx.x * 256 + threadIdx.x;
  if (e < NE) {
    const int pos = atomicAdd(&cursor[dst[e]], 1);
    csrc[pos] = src[e];
  }
}

// ============ aggregation: xin[v] = bf16( h[v] + sum_{u->v} h[u] ) ============
__global__ __launch_bounds__(256) void agg_f32_k(const float* __restrict__ h,
                                                 const int* __restrict__ rowptr,
                                                 const int* __restrict__ csrc,
                                                 unsigned short* __restrict__ xout) {
  const int node = blockIdx.x * 4 + (threadIdx.x >> 6);
  const int lane = threadIdx.x & 63;
  const f32x4* row = reinterpret_cast<const f32x4*>(h + (size_t)node * DD + lane * 8);
  f32x4 a0 = row[0], a1 = row[1];
  const int p1 = rowptr[node + 1];
  for (int p = rowptr[node]; p < p1; ++p) {
    const int s = csrc[p];
    const f32x4* rs = reinterpret_cast<const f32x4*>(h + (size_t)s * DD + lane * 8);
    a0 += rs[0];
    a1 += rs[1];
  }
  f32x8 vf;
  vf[0]=a0[0]; vf[1]=a0[1]; vf[2]=a0[2]; vf[3]=a0[3];
  vf[4]=a1[0]; vf[5]=a1[1]; vf[6]=a1[2]; vf[7]=a1[3];
  *reinterpret_cast<bf16x8*>(xout + (size_t)node * DD + lane * 8) =
      __builtin_convertvector(vf, bf16x8);
}

__global__ __launch_bounds__(256) void agg_bf16_k(const unsigned short* __restrict__ h,
                                                  const int* __restrict__ rowptr,
                                                  const int* __restrict__ csrc,
                                                  unsigned short* __restrict__ xout) {
  const int node = blockIdx.x * 4 + (threadIdx.x >> 6);
  const int lane = threadIdx.x & 63;
  u16x8 sv = *reinterpret_cast<const u16x8*>(h + (size_t)node * DD + lane * 8);
  f32x8 acc = __builtin_convertvector(__builtin_bit_cast(bf16x8, sv), f32x8);
  const int p1 = rowptr[node + 1];
  for (int p = rowptr[node]; p < p1; ++p) {
    const int s = csrc[p];
    u16x8 rv = *reinterpret_cast<const u16x8*>(h + (size_t)s * DD + lane * 8);
    acc += __builtin_convertvector(__builtin_bit_cast(bf16x8, rv), f32x8);
  }
  *reinterpret_cast<bf16x8*>(xout + (size_t)node * DD + lane * 8) =
      __builtin_convertvector(acc, bf16x8);
}

// ============ GEMM1: Z = bf16( xin @ W1bf^T ), stats += colsum(z), colsum(z^2) ============
// m97 structure: 128x128 tile, BK=64, global_load_lds width-16, linear LDS, 2 barriers/K-step.
__global__ __launch_bounds__(256) void gemm1_k(
    const unsigned short* __restrict__ A, const unsigned short* __restrict__ B,
    unsigned short* __restrict__ Z, float* __restrict__ stats) {
  __shared__ unsigned short lA[128 * 64];
  __shared__ unsigned short lB[128 * 64];
  const int tid = threadIdx.x;
  const int brow = blockIdx.y * 128;
  const int bcol = blockIdx.x * 128;
  const int lane = tid & 63;
  const int w = tid >> 6;
  const int wr = (w >> 1) * 64;
  const int wc = (w & 1) * 64;
  const int fr = lane & 15;
  const int fg = lane >> 4;
  const int lrow = lane >> 3;
  const int lcb = (lane & 7) * 16;

  const char* Ab = (const char*)A + (size_t)brow * 1024;
  const char* Bb = (const char*)B + (size_t)bcol * 1024;

  f32x4 acc[4][4] = {};

  for (int kt = 0; kt < 8; ++kt) {
    __syncthreads();
#pragma unroll
    for (int i = 0; i < 4; ++i) {
      const int s = w * 4 + i;
      const size_t go = (size_t)(s * 8 + lrow) * 1024 + kt * 128 + lcb;
      gload16(Ab + go, &lA[s * 512]);
      gload16(Bb + go, &lB[s * 512]);
    }
    __syncthreads();
#pragma unroll
    for (int kk = 0; kk < 2; ++kk) {
      bf16x8 av[4], bv[4];
#pragma unroll
      for (int i = 0; i < 4; ++i)
        av[i] = *reinterpret_cast<const bf16x8*>(&lA[(wr + i * 16 + fr) * 64 + kk * 32 + fg * 8]);
#pragma unroll
      for (int j = 0; j < 4; ++j)
        bv[j] = *reinterpret_cast<const bf16x8*>(&lB[(wc + j * 16 + fr) * 64 + kk * 32 + fg * 8]);
#pragma unroll
      for (int i = 0; i < 4; ++i)
#pragma unroll
        for (int j = 0; j < 4; ++j)
          acc[i][j] = __builtin_amdgcn_mfma_f32_16x16x32_bf16(av[i], bv[j], acc[i][j], 0, 0, 0);
    }
  }

#pragma unroll
  for (int j = 0; j < 4; ++j) {
    const int col = bcol + wc + j * 16 + fr;
    float s1 = 0.f, s2 = 0.f;
#pragma unroll
    for (int i = 0; i < 4; ++i) {
      const int rb = brow + wr + i * 16 + fg * 4;
#pragma unroll
      for (int r = 0; r < 4; ++r) {
        const float v = acc[i][j][r];
        s1 += v;
        s2 += v * v;  // pad rows: A==0 -> acc==0 -> no contribution
        __bf16 b = (__bf16)v;
        Z[(size_t)(rb + r) * DD + col] = __builtin_bit_cast(unsigned short, b);
      }
    }
    s1 += __shfl_down(s1, 32);
    s2 += __shfl_down(s2, 32);
    s1 += __shfl_down(s1, 16);
    s2 += __shfl_down(s2, 16);
    if (lane < 16) {
      atomicAdd(&stats[col], s1);
      atomicAdd(&stats[DD + col], s2);
    }
  }
}

// ============ BN finalize ============
__global__ void bnfin_k(const float* __restrict__ stats, const float* __restrict__ gamma,
                        const float* __restrict__ beta, float* __restrict__ scsh) {
  const int n = threadIdx.x;
  const float inv = 1.0f / (float)NN;
  const float mu = stats[n] * inv;
  const float var = stats[DD + n] * inv - mu * mu;
  const float sc = rsqrtf(var + 1e-5f) * gamma[n];
  scsh[n] = sc;
  scsh[DD + n] = beta[n] - mu * sc;
}

// ============ BN+ReLU apply: act = relu(z*sc+sh) (bf16), pad rows -> 0 ============
__global__ __launch_bounds__(256) void act_k(const unsigned short* __restrict__ Zin,
                                             const float* __restrict__ scsh,
                                             unsigned short* __restrict__ Aout) {
  const int gid = blockIdx.x * 256 + threadIdx.x;
  const int row = gid >> 6;
  const int c0 = (gid & 63) * 8;
  u16x8 o = {};
  if (row < NN) {
    u16x8 zv = *reinterpret_cast<const u16x8*>(Zin + (size_t)row * DD + c0);
    f32x8 zf = __builtin_convertvector(__builtin_bit_cast(bf16x8, zv), f32x8);
    const f32x4* scp = reinterpret_cast<const f32x4*>(scsh + c0);
    const f32x4* shp = reinterpret_cast<const f32x4*>(scsh + DD + c0);
    f32x4 sc0 = scp[0], sc1 = scp[1], sh0 = shp[0], sh1 = shp[1];
    f32x8 vf;
#pragma unroll
    for (int q = 0; q < 4; ++q) {
      vf[q]     = fmaxf(zf[q]     * sc0[q] + sh0[q], 0.f);
      vf[q + 4] = fmaxf(zf[q + 4] * sc1[q] + sh1[q], 0.f);
    }
    o = __builtin_bit_cast(u16x8, __builtin_convertvector(vf, bf16x8));
  }
  *reinterpret_cast<u16x8*>(Aout + (size_t)row * DD + c0) = o;
}

// ============ GEMM2: H = bf16(act @ W2bf^T + b2), fused colsum ============
__global__ __launch_bounds__(256) void gemm2_k(
    const unsigned short* __restrict__ A, const unsigned short* __restrict__ B,
    const float* __restrict__ b2, unsigned short* __restrict__ H,
    float* __restrict__ colsum, const int write_h, const int do_colsum) {
  __shared__ unsigned short lA[128 * 64];
  __shared__ unsigned short lB[128 * 64];
  const int tid = threadIdx.x;
  const int brow = blockIdx.y * 128;
  const int bcol = blockIdx.x * 128;
  const int lane = tid & 63;
  const int w = tid >> 6;
  const int wr = (w >> 1) * 64;
  const int wc = (w & 1) * 64;
  const int fr = lane & 15;
  const int fg = lane >> 4;
  const int lrow = lane >> 3;
  const int lcb = (lane & 7) * 16;

  const char* Ab = (const char*)A + (size_t)brow * 1024;
  const char* Bb = (const char*)B + (size_t)bcol * 1024;

  f32x4 acc[4][4] = {};

  for (int kt = 0; kt < 8; ++kt) {
    __syncthreads();
#pragma unroll
    for (int i = 0; i < 4; ++i) {
      const int s = w * 4 + i;
      const size_t go = (size_t)(s * 8 + lrow) * 1024 + kt * 128 + lcb;
      gload16(Ab + go, &lA[s * 512]);
      gload16(Bb + go, &lB[s * 512]);
    }
    __syncthreads();
#pragma unroll
    for (int kk = 0; kk < 2; ++kk) {
      bf16x8 av[4], bv[4];
#pragma unroll
      for (int i = 0; i < 4; ++i)
        av[i] = *reinterpret_cast<const bf16x8*>(&lA[(wr + i * 16 + fr) * 64 + kk * 32 + fg * 8]);
#pragma unroll
      for (int j = 0; j < 4; ++j)
        bv[j] = *reinterpret_cast<const bf16x8*>(&lB[(wc + j * 16 + fr) * 64 + kk * 32 + fg * 8]);
#pragma unroll
      for (int i = 0; i < 4; ++i)
#pragma unroll
        for (int j = 0; j < 4; ++j)
          acc[i][j] = __builtin_amdgcn_mfma_f32_16x16x32_bf16(av[i], bv[j], acc[i][j], 0, 0, 0);
    }
  }

#pragma unroll
  for (int j = 0; j < 4; ++j) {
    const int col = bcol + wc + j * 16 + fr;
    const float bb = b2[col];
    float s1 = 0.f;
#pragma unroll
    for (int i = 0; i < 4; ++i) {
      const int rb = brow + wr + i * 16 + fg * 4;
#pragma unroll
      for (int r = 0; r < 4; ++r) {
        const float v = acc[i][j][r];
        s1 += v;  // pad rows: act==0 -> acc==0
        if (write_h) {
          __bf16 b = (__bf16)(v + bb);
          H[(size_t)(rb + r) * DD + col] = __builtin_bit_cast(unsigned short, b);
        }
      }
    }
    if (do_colsum) {
      s1 += __shfl_down(s1, 32);
      s1 += __shfl_down(s1, 16);
      if (lane < 16) atomicAdd(&colsum[col], s1);
    }
  }
}

// ============ final outputs ============
__global__ void out_k(const float* __restrict__ colsum, const float* __restrict__ b2_all,
                      float* __restrict__ out) {
  const int n = threadIdx.x;
  const float inv = 1.0f / (float)NN;
  out[n]      = colsum[DD + n] * inv + b2_all[3 * DD + n];  // outs[-1] = layer 3
  out[DD + n] = colsum[n] * inv      + b2_all[2 * DD + n];  // outs[-2] = layer 2
}

extern "C" void kernel_launch(void* const* d_in, const int* in_sizes, int n_in,
                              void* d_out, int out_size, void* d_ws, size_t ws_size,
                              hipStream_t stream) {
  const float* x     = (const float*)d_in[0];
  const float* W1    = (const float*)d_in[1];
  // d_in[2] = b1: cancels exactly in training-mode BatchNorm -> unused
  const float* gamma = (const float*)d_in[3];
  const float* beta  = (const float*)d_in[4];
  const float* W2    = (const float*)d_in[5];
  const float* b2    = (const float*)d_in[6];
  const int*   src   = (const int*)d_in[7];
  const int*   dst   = (const int*)d_in[8];
  float* out = (float*)d_out;

  char* ws = (char*)d_ws;
  const size_t ABYTES = (size_t)MPAD * DD * 2;  // 51,380,224
  unsigned short* xin    = (unsigned short*)(ws);                 // A buffer
  unsigned short* zh     = (unsigned short*)(ws + ABYTES);        // z and h share (disjoint lifetimes)
  unsigned short* act    = (unsigned short*)(ws + 2 * ABYTES);
  unsigned short* wb1    = (unsigned short*)(ws + 3 * ABYTES);                 // 2,097,152 B
  unsigned short* wb2    = (unsigned short*)(ws + 3 * ABYTES + 2097152);       // 2,097,152 B
  int*            rowptr = (int*)(ws + 158334976);
  int*            cursor = (int*)(ws + 158535936);
  int*            csrc   = (int*)(ws + 158735936);
  float*          stats  = (float*)(ws + 159400000);
  float*          colsum = (float*)(ws + 159404096);
  float*          scsh   = (float*)(ws + 159408192);

  // weights -> bf16 (once)
  wconv_k<<<512, 256, 0, stream>>>(W1, W2, wb1, wb2);
  // zero xin pad rows (agg never writes them; zeros propagate through the pipeline)
  hipMemsetAsync(xin + (size_t)NN * DD, 0, (size_t)(MPAD - NN) * DD * 2, stream);

  // CSR build (once)
  hipMemsetAsync(cursor, 0, NN * sizeof(int), stream);
  count_k<<<(NE + 255) / 256, 256, 0, stream>>>(dst, cursor);
  scan_k<<<1, 1024, 0, stream>>>(cursor, rowptr, cursor);
  fill_k<<<(NE + 255) / 256, 256, 0, stream>>>(src, dst, cursor, csrc);

  hipMemsetAsync(colsum, 0, 2 * DD * sizeof(float), stream);

  dim3 gg(DD / 128, MPAD / 128);  // (4, 392)
  for (int l = 0; l < 4; ++l) {
    if (l == 0)
      agg_f32_k<<<NN / 4, 256, 0, stream>>>(x, rowptr, csrc, xin);
    else
      agg_bf16_k<<<NN / 4, 256, 0, stream>>>(zh, rowptr, csrc, xin);
    hipMemsetAsync(stats, 0, 2 * DD * sizeof(float), stream);
    gemm1_k<<<gg, 256, 0, stream>>>(xin, wb1 + (size_t)l * DD * DD, zh, stats);
    bnfin_k<<<1, DD, 0, stream>>>(stats, gamma + l * DD, beta + l * DD, scsh);
    act_k<<<MPAD * DD / 8 / 256, 256, 0, stream>>>(zh, scsh, act);
    const int slot = (l == 2) ? 0 : ((l == 3) ? 1 : -1);
    gemm2_k<<<gg, 256, 0, stream>>>(act, wb2 + (size_t)l * DD * DD, b2 + l * DD,
                                    zh, colsum + (slot == 1 ? DD : 0),
                                    (l < 3) ? 1 : 0, (slot >= 0) ? 1 : 0);
  }
  out_k<<<1, DD, 0, stream>>>(colsum, b2, out);
}

// Round 4
// 842.948 us; speedup vs baseline: 6.1698x; 1.0542x over previous
//
#include <hip/hip_runtime.h>

#define NN 50000
#define MPAD 50176  // 392 * 128
#define DD 512
#define NE 150000

typedef float f32x4 __attribute__((ext_vector_type(4)));
typedef float f32x8 __attribute__((ext_vector_type(8)));
typedef __bf16 bf16x8 __attribute__((ext_vector_type(8)));
typedef unsigned short u16x8 __attribute__((ext_vector_type(8)));

__device__ __forceinline__ void gload16(const void* g, void* l) {
  __builtin_amdgcn_global_load_lds((const __attribute__((address_space(1))) void*)g,
                                   (__attribute__((address_space(3))) void*)l, 16, 0, 0);
}

// ============ weight convert: f32 -> bf16 ============
__global__ void wconv_k(const float* __restrict__ W1, const float* __restrict__ W2,
                        unsigned short* __restrict__ o1, unsigned short* __restrict__ o2) {
  const size_t i = ((size_t)blockIdx.x * 256 + threadIdx.x) * 8;
  {
    const f32x4* g = reinterpret_cast<const f32x4*>(W1 + i);
    f32x4 a = g[0], b = g[1];
    f32x8 v;
    v[0]=a[0]; v[1]=a[1]; v[2]=a[2]; v[3]=a[3]; v[4]=b[0]; v[5]=b[1]; v[6]=b[2]; v[7]=b[3];
    *reinterpret_cast<bf16x8*>(o1 + i) = __builtin_convertvector(v, bf16x8);
  }
  {
    const f32x4* g = reinterpret_cast<const f32x4*>(W2 + i);
    f32x4 a = g[0], b = g[1];
    f32x8 v;
    v[0]=a[0]; v[1]=a[1]; v[2]=a[2]; v[3]=a[3]; v[4]=b[0]; v[5]=b[1]; v[6]=b[2]; v[7]=b[3];
    *reinterpret_cast<bf16x8*>(o2 + i) = __builtin_convertvector(v, bf16x8);
  }
}

// ============ CSR build ============
__global__ void count_k(const int* __restrict__ dst, int* __restrict__ cnt) {
  const int e = blockIdx.x * 256 + threadIdx.x;
  if (e < NE) atomicAdd(&cnt[dst[e]], 1);
}

__global__ __launch_bounds__(1024) void scan_k(const int* __restrict__ cnt,
                                               int* __restrict__ rowptr,
                                               int* __restrict__ cursor) {
  __shared__ int wsum[16];
  __shared__ int base_s;
  if (threadIdx.x == 0) base_s = 0;
  __syncthreads();
  const int lane = threadIdx.x & 63;
  const int wid = threadIdx.x >> 6;
  for (int c0 = 0; c0 < NN; c0 += 1024) {
    const int i = c0 + threadIdx.x;
    const int v = (i < NN) ? cnt[i] : 0;
    int incl = v;
#pragma unroll
    for (int d = 1; d < 64; d <<= 1) {
      int t = __shfl_up(incl, d);
      if (lane >= d) incl += t;
    }
    if (lane == 63) wsum[wid] = incl;
    __syncthreads();
    if (wid == 0 && lane < 16) {
      int wv = wsum[lane];
#pragma unroll
      for (int d = 1; d < 16; d <<= 1) {
        int t = __shfl_up(wv, d);
        if (lane >= d) wv += t;
      }
      wsum[lane] = wv;
    }
    __syncthreads();
    const int waveoff = wid ? wsum[wid - 1] : 0;
    const int excl = base_s + waveoff + incl - v;
    if (i < NN) {
      rowptr[i] = excl;
      cursor[i] = excl;
    }
    __syncthreads();
    if (threadIdx.x == 0) base_s += wsum[15];
    __syncthreads();
  }
  if (threadIdx.x == 0) rowptr[NN] = base_s;
}

__global__ void fill_k(const int* __restrict__ src, const int* __restrict__ dst,
                       int* __restrict__ cursor, int* __restrict__ csrc) {
  const int e = blockIdx.x * 256 + threadIdx.x;
  if (e < NE) {
    const int pos = atomicAdd(&cursor[dst[e]], 1);
    csrc[pos] = src[e];
  }
}

// ============ aggregation ============
__global__ __launch_bounds__(256) void agg_f32_k(const float* __restrict__ h,
                                                 const int* __restrict__ rowptr,
                                                 const int* __restrict__ csrc,
                                                 unsigned short* __restrict__ xout) {
  const int node = blockIdx.x * 4 + (threadIdx.x >> 6);
  const int lane = threadIdx.x & 63;
  const f32x4* row = reinterpret_cast<const f32x4*>(h + (size_t)node * DD + lane * 8);
  f32x4 a0 = row[0], a1 = row[1];
  const int p1 = rowptr[node + 1];
  for (int p = rowptr[node]; p < p1; ++p) {
    const int s = csrc[p];
    const f32x4* rs = reinterpret_cast<const f32x4*>(h + (size_t)s * DD + lane * 8);
    a0 += rs[0];
    a1 += rs[1];
  }
  f32x8 vf;
  vf[0]=a0[0]; vf[1]=a0[1]; vf[2]=a0[2]; vf[3]=a0[3];
  vf[4]=a1[0]; vf[5]=a1[1]; vf[6]=a1[2]; vf[7]=a1[3];
  *reinterpret_cast<bf16x8*>(xout + (size_t)node * DD + lane * 8) =
      __builtin_convertvector(vf, bf16x8);
}

__global__ __launch_bounds__(256) void agg_bf16_k(const unsigned short* __restrict__ h,
                                                  const int* __restrict__ rowptr,
                                                  const int* __restrict__ csrc,
                                                  unsigned short* __restrict__ xout) {
  const int node = blockIdx.x * 4 + (threadIdx.x >> 6);
  const int lane = threadIdx.x & 63;
  u16x8 sv = *reinterpret_cast<const u16x8*>(h + (size_t)node * DD + lane * 8);
  f32x8 acc = __builtin_convertvector(__builtin_bit_cast(bf16x8, sv), f32x8);
  const int p1 = rowptr[node + 1];
  for (int p = rowptr[node]; p < p1; ++p) {
    const int s = csrc[p];
    u16x8 rv = *reinterpret_cast<const u16x8*>(h + (size_t)s * DD + lane * 8);
    acc += __builtin_convertvector(__builtin_bit_cast(bf16x8, rv), f32x8);
  }
  *reinterpret_cast<bf16x8*>(xout + (size_t)node * DD + lane * 8) =
      __builtin_convertvector(acc, bf16x8);
}

// ============ GEMM1: Z = bf16( xin @ W1bf^T ), stats += colsum(z), colsum(z^2) ============
// 128x256 tile, 8 waves (64x64 each), BK=64, global_load_lds, 2 blocks/CU.
__global__ __launch_bounds__(512, 4) void gemm1_k(
    const unsigned short* __restrict__ A, const unsigned short* __restrict__ B,
    unsigned short* __restrict__ Z, float* __restrict__ stats) {
  __shared__ unsigned short lA[128 * 64];  // 16 KB
  __shared__ unsigned short lB[256 * 64];  // 32 KB
  const int tid = threadIdx.x;
  const int lane = tid & 63;
  const int w = tid >> 6;          // 0..7
  const int rg = (w >> 2) * 64;    // 0,64
  const int cg = (w & 3) * 64;     // 0..192
  const int fr = lane & 15;
  const int fg = lane >> 4;
  const int brow = blockIdx.y * 128;
  const int bcol = blockIdx.x * 256;
  const char* Ab = (const char*)A + (size_t)brow * 1024;
  const char* Bb = (const char*)B + (size_t)bcol * 1024;
  const int srow = tid >> 3;            // 0..63
  const int sc16 = (tid & 7) * 16;      // byte offset within 128B K-slice
  const int sce = (tid & 7) * 8;        // element offset

  f32x4 acc[4][4] = {};

  for (int kt = 0; kt < 8; ++kt) {
    const int kb = kt * 128;
    __syncthreads();
#pragma unroll
    for (int i = 0; i < 2; ++i)
      gload16(Ab + (size_t)(i * 64 + srow) * 1024 + kb + sc16, &lA[(i * 64 + srow) * 64 + sce]);
#pragma unroll
    for (int i = 0; i < 4; ++i)
      gload16(Bb + (size_t)(i * 64 + srow) * 1024 + kb + sc16, &lB[(i * 64 + srow) * 64 + sce]);
    __syncthreads();
#pragma unroll
    for (int kk = 0; kk < 2; ++kk) {
      bf16x8 av[4], bv[4];
#pragma unroll
      for (int i = 0; i < 4; ++i)
        av[i] = *reinterpret_cast<const bf16x8*>(&lA[(rg + i * 16 + fr) * 64 + kk * 32 + fg * 8]);
#pragma unroll
      for (int j = 0; j < 4; ++j)
        bv[j] = *reinterpret_cast<const bf16x8*>(&lB[(cg + j * 16 + fr) * 64 + kk * 32 + fg * 8]);
#pragma unroll
      for (int i = 0; i < 4; ++i)
#pragma unroll
        for (int j = 0; j < 4; ++j)
          acc[i][j] = __builtin_amdgcn_mfma_f32_16x16x32_bf16(av[i], bv[j], acc[i][j], 0, 0, 0);
    }
  }

#pragma unroll
  for (int j = 0; j < 4; ++j) {
    const int col = bcol + cg + j * 16 + fr;
    float s1 = 0.f, s2 = 0.f;
#pragma unroll
    for (int i = 0; i < 4; ++i) {
      const int rb = brow + rg + i * 16 + fg * 4;
#pragma unroll
      for (int r = 0; r < 4; ++r) {
        const float v = acc[i][j][r];
        s1 += v;
        s2 += v * v;  // pad rows: xin==0 -> acc==0 -> no contribution
        __bf16 b = (__bf16)v;
        Z[(size_t)(rb + r) * DD + col] = __builtin_bit_cast(unsigned short, b);
      }
    }
    s1 += __shfl_down(s1, 32);
    s2 += __shfl_down(s2, 32);
    s1 += __shfl_down(s1, 16);
    s2 += __shfl_down(s2, 16);
    if (lane < 16) {
      atomicAdd(&stats[col], s1);
      atomicAdd(&stats[DD + col], s2);
    }
  }
}

// ============ BN finalize ============
__global__ void bnfin_k(const float* __restrict__ stats, const float* __restrict__ gamma,
                        const float* __restrict__ beta, float* __restrict__ scsh) {
  const int n = threadIdx.x;
  const float inv = 1.0f / (float)NN;
  const float mu = stats[n] * inv;
  const float var = stats[DD + n] * inv - mu * mu;
  const float sc = rsqrtf(var + 1e-5f) * gamma[n];
  scsh[n] = sc;
  scsh[DD + n] = beta[n] - mu * sc;
}

// ============ GEMM2: H = bf16(relu(z*sc+sh) @ W2bf^T + b2), fused colsum ============
// A-staging is reg-staged with BN+ReLU fused (act pass eliminated); B via gload16.
__global__ __launch_bounds__(512, 4) void gemm2_k(
    const unsigned short* __restrict__ Zin, const unsigned short* __restrict__ B,
    const float* __restrict__ scsh, const float* __restrict__ b2,
    unsigned short* __restrict__ H, float* __restrict__ colsum,
    const int write_h, const int do_colsum) {
  __shared__ unsigned short lA[128 * 64];  // 16 KB
  __shared__ unsigned short lB[256 * 64];  // 32 KB
  const int tid = threadIdx.x;
  const int lane = tid & 63;
  const int w = tid >> 6;
  const int rg = (w >> 2) * 64;
  const int cg = (w & 3) * 64;
  const int fr = lane & 15;
  const int fg = lane >> 4;
  const int brow = blockIdx.y * 128;
  const int bcol = blockIdx.x * 256;
  const char* Bb = (const char*)B + (size_t)bcol * 1024;
  const int srow = tid >> 3;        // 0..63
  const int sc16 = (tid & 7) * 16;
  const int sce = (tid & 7) * 8;
  const int r0 = brow + srow;       // first staged row
  const int r1 = r0 + 64;           // second staged row

  f32x4 acc[4][4] = {};

  // prefetch z slices for kt=0
  u16x8 z0 = *reinterpret_cast<const u16x8*>(Zin + (size_t)r0 * DD + sce);
  u16x8 z1 = *reinterpret_cast<const u16x8*>(Zin + (size_t)r1 * DD + sce);

  for (int kt = 0; kt < 8; ++kt) {
    // BN+ReLU transform in regs
    const int c0 = kt * 64 + sce;
    const f32x4* scp = reinterpret_cast<const f32x4*>(scsh + c0);
    const f32x4* shp = reinterpret_cast<const f32x4*>(scsh + DD + c0);
    f32x4 sca = scp[0], scb = scp[1], sha = shp[0], shb = shp[1];
    f32x8 f0 = __builtin_convertvector(__builtin_bit_cast(bf16x8, z0), f32x8);
    f32x8 f1 = __builtin_convertvector(__builtin_bit_cast(bf16x8, z1), f32x8);
    f32x8 a0 = {}, a1 = {};
    if (r0 < NN) {
#pragma unroll
      for (int q = 0; q < 4; ++q) {
        a0[q]     = fmaxf(f0[q]     * sca[q] + sha[q], 0.f);
        a0[q + 4] = fmaxf(f0[q + 4] * scb[q] + shb[q], 0.f);
      }
    }
    if (r1 < NN) {
#pragma unroll
      for (int q = 0; q < 4; ++q) {
        a1[q]     = fmaxf(f1[q]     * sca[q] + sha[q], 0.f);
        a1[q + 4] = fmaxf(f1[q + 4] * scb[q] + shb[q], 0.f);
      }
    }
    bf16x8 ab0 = __builtin_convertvector(a0, bf16x8);
    bf16x8 ab1 = __builtin_convertvector(a1, bf16x8);

    __syncthreads();  // prev compute done, LDS free
    *reinterpret_cast<bf16x8*>(&lA[srow * 64 + sce]) = ab0;
    *reinterpret_cast<bf16x8*>(&lA[(srow + 64) * 64 + sce]) = ab1;
    const int kb = kt * 128;
#pragma unroll
    for (int i = 0; i < 4; ++i)
      gload16(Bb + (size_t)(i * 64 + srow) * 1024 + kb + sc16, &lB[(i * 64 + srow) * 64 + sce]);
    __syncthreads();  // staged (drains gloads + ds_writes)

    if (kt < 7) {  // prefetch next z slices; overlaps MFMA phase
      const size_t off = (size_t)(kt + 1) * 64 + sce;
      z0 = *reinterpret_cast<const u16x8*>(Zin + (size_t)r0 * DD + off);
      z1 = *reinterpret_cast<const u16x8*>(Zin + (size_t)r1 * DD + off);
    }

#pragma unroll
    for (int kk = 0; kk < 2; ++kk) {
      bf16x8 av[4], bv[4];
#pragma unroll
      for (int i = 0; i < 4; ++i)
        av[i] = *reinterpret_cast<const bf16x8*>(&lA[(rg + i * 16 + fr) * 64 + kk * 32 + fg * 8]);
#pragma unroll
      for (int j = 0; j < 4; ++j)
        bv[j] = *reinterpret_cast<const bf16x8*>(&lB[(cg + j * 16 + fr) * 64 + kk * 32 + fg * 8]);
#pragma unroll
      for (int i = 0; i < 4; ++i)
#pragma unroll
        for (int j = 0; j < 4; ++j)
          acc[i][j] = __builtin_amdgcn_mfma_f32_16x16x32_bf16(av[i], bv[j], acc[i][j], 0, 0, 0);
    }
  }

#pragma unroll
  for (int j = 0; j < 4; ++j) {
    const int col = bcol + cg + j * 16 + fr;
    const float bb = b2[col];
    float s1 = 0.f;
#pragma unroll
    for (int i = 0; i < 4; ++i) {
      const int rb = brow + rg + i * 16 + fg * 4;
#pragma unroll
      for (int r = 0; r < 4; ++r) {
        const float v = acc[i][j][r];
        s1 += v;  // pad rows: staged act==0 -> acc==0
        if (write_h) {
          __bf16 b = (__bf16)(v + bb);
          H[(size_t)(rb + r) * DD + col] = __builtin_bit_cast(unsigned short, b);
        }
      }
    }
    if (do_colsum) {
      s1 += __shfl_down(s1, 32);
      s1 += __shfl_down(s1, 16);
      if (lane < 16) atomicAdd(&colsum[col], s1);
    }
  }
}

// ============ final outputs ============
__global__ void out_k(const float* __restrict__ colsum, const float* __restrict__ b2_all,
                      float* __restrict__ out) {
  const int n = threadIdx.x;
  const float inv = 1.0f / (float)NN;
  out[n]      = colsum[DD + n] * inv + b2_all[3 * DD + n];  // outs[-1] = layer 3
  out[DD + n] = colsum[n] * inv      + b2_all[2 * DD + n];  // outs[-2] = layer 2
}

extern "C" void kernel_launch(void* const* d_in, const int* in_sizes, int n_in,
                              void* d_out, int out_size, void* d_ws, size_t ws_size,
                              hipStream_t stream) {
  const float* x     = (const float*)d_in[0];
  const float* W1    = (const float*)d_in[1];
  // d_in[2] = b1: cancels exactly in training-mode BatchNorm -> unused
  const float* gamma = (const float*)d_in[3];
  const float* beta  = (const float*)d_in[4];
  const float* W2    = (const float*)d_in[5];
  const float* b2    = (const float*)d_in[6];
  const int*   src   = (const int*)d_in[7];
  const int*   dst   = (const int*)d_in[8];
  float* out = (float*)d_out;

  char* ws = (char*)d_ws;
  const size_t ABYTES = (size_t)MPAD * DD * 2;  // 51,380,224
  unsigned short* xin    = (unsigned short*)(ws);
  unsigned short* z      = (unsigned short*)(ws + ABYTES);
  unsigned short* h      = (unsigned short*)(ws + 2 * ABYTES);
  unsigned short* wb1    = (unsigned short*)(ws + 3 * ABYTES);
  unsigned short* wb2    = (unsigned short*)(ws + 3 * ABYTES + 2097152);
  int*            rowptr = (int*)(ws + 3 * ABYTES + 4194304);
  int*            cursor = (int*)(ws + 3 * ABYTES + 4494304);
  int*            csrc   = (int*)(ws + 3 * ABYTES + 4694304);
  float*          stats  = (float*)(ws + 3 * ABYTES + 5394304);
  float*          colsum = (float*)(ws + 3 * ABYTES + 5398400);
  float*          scsh   = (float*)(ws + 3 * ABYTES + 5402496);

  // weights -> bf16 (once)
  wconv_k<<<512, 256, 0, stream>>>(W1, W2, wb1, wb2);
  // zero xin pad rows once (agg never writes them; zeros keep stats/colsum exact)
  hipMemsetAsync(xin + (size_t)NN * DD, 0, (size_t)(MPAD - NN) * DD * 2, stream);

  // CSR build (once)
  hipMemsetAsync(cursor, 0, NN * sizeof(int), stream);
  count_k<<<(NE + 255) / 256, 256, 0, stream>>>(dst, cursor);
  scan_k<<<1, 1024, 0, stream>>>(cursor, rowptr, cursor);
  fill_k<<<(NE + 255) / 256, 256, 0, stream>>>(src, dst, cursor, csrc);

  hipMemsetAsync(colsum, 0, 2 * DD * sizeof(float), stream);

  dim3 gg(DD / 256, MPAD / 128);  // (2, 392)
  for (int l = 0; l < 4; ++l) {
    if (l == 0)
      agg_f32_k<<<NN / 4, 256, 0, stream>>>(x, rowptr, csrc, xin);
    else
      agg_bf16_k<<<NN / 4, 256, 0, stream>>>(h, rowptr, csrc, xin);
    hipMemsetAsync(stats, 0, 2 * DD * sizeof(float), stream);
    gemm1_k<<<gg, 512, 0, stream>>>(xin, wb1 + (size_t)l * DD * DD, z, stats);
    bnfin_k<<<1, DD, 0, stream>>>(stats, gamma + l * DD, beta + l * DD, scsh);
    const int slot = (l == 2) ? 0 : ((l == 3) ? 1 : -1);
    gemm2_k<<<gg, 512, 0, stream>>>(z, wb2 + (size_t)l * DD * DD, scsh, b2 + l * DD,
                                    h, colsum + (slot == 1 ? DD : 0),
                                    (l < 3) ? 1 : 0, (slot >= 0) ? 1 : 0);
  }
  out_k<<<1, DD, 0, stream>>>(colsum, b2, out);
}